// Round 9
// baseline (138.268 us; speedup 1.0000x reference)
//
#include <hip/hip_runtime.h>
#include <math.h>

#define NB 16
#define CB 256
#define MIP 8
#define EPSV 1e-5f
#define GRID 256
#define PPB 16   // planes per block

// One persistent block per CU (VGPR>256 forces 1 block/CU, so all 256 blocks
// are co-resident and the grid barrier cannot deadlock).
__global__ __launch_bounds__(256, 1) void k_fused(
    const float* __restrict__ x, const float* __restrict__ res,
    const float* __restrict__ w1, const float* __restrict__ b1,
    const float* __restrict__ gamma, const float* __restrict__ beta,
    const float* __restrict__ mean, const float* __restrict__ var,
    const float* __restrict__ w2, const float* __restrict__ b2,
    const float* __restrict__ w3, const float* __restrict__ b3,
    float* __restrict__ out, float* __restrict__ xh, float* __restrict__ xw,
    unsigned* __restrict__ bar)
{
    int blk = blockIdx.x;
    int t   = threadIdx.x;
    int n   = blk >> 4;                           // image index (16 blocks per n)
    size_t p0 = (size_t)blk * PPB;                // first global plane of block
    const float4* px4 = (const float4*)x   + p0 * 1024;
    const float4* pr4 = (const float4*)res + p0 * 1024;
    float4*       po4 = (float4*)out       + p0 * 1024;

    __shared__ float smem[4096];                  // ph1: col partials [16][4][64]; ph2: pool chunk [32][128]
    __shared__ float yl[MIP * 128];
    __shared__ float ah_l[PPB * 64];
    __shared__ float aw_l[PPB * 64];

    int wv  = t >> 6;                             // wave 0..3
    int g16 = t >> 4;                             // 0..15 (row sub-group)
    int l16 = t & 15;

    // ---- Phase 1: stream x (into regs), add res, reduce rows & cols ----
    float4 s[PPB][4];                             // 256 VGPRs, static-indexed only
#pragma unroll
    for (int p = 0; p < PPB; ++p)
#pragma unroll
        for (int j = 0; j < 4; ++j)
            s[p][j] = px4[p * 1024 + j * 256 + t];
#pragma unroll
    for (int p = 0; p < PPB; ++p)
#pragma unroll
        for (int j = 0; j < 4; ++j) {
            float4 r = pr4[p * 1024 + j * 256 + t];
            s[p][j].x += r.x; s[p][j].y += r.y;
            s[p][j].z += r.z; s[p][j].w += r.w;
        }

#pragma unroll
    for (int p = 0; p < PPB; ++p) {
        float cs0 = 0.f, cs1 = 0.f, cs2 = 0.f, cs3 = 0.f;
#pragma unroll
        for (int j = 0; j < 4; ++j) {
            float4 v = s[p][j];
            cs0 += v.x; cs1 += v.y; cs2 += v.z; cs3 += v.w;
            float rs = (v.x + v.y) + (v.z + v.w);
            rs += __shfl_xor(rs, 1);
            rs += __shfl_xor(rs, 2);
            rs += __shfl_xor(rs, 4);
            rs += __shfl_xor(rs, 8);
            if (l16 == 0)
                xh[(p0 + p) * 64 + j * 16 + g16] = rs * 0.015625f;
        }
        cs0 += __shfl_xor(cs0, 16); cs0 += __shfl_xor(cs0, 32);
        cs1 += __shfl_xor(cs1, 16); cs1 += __shfl_xor(cs1, 32);
        cs2 += __shfl_xor(cs2, 16); cs2 += __shfl_xor(cs2, 32);
        cs3 += __shfl_xor(cs3, 16); cs3 += __shfl_xor(cs3, 32);
        if ((t & 63) < 16) {
            float* d = &smem[p * 256 + wv * 64 + l16 * 4];
            d[0] = cs0; d[1] = cs1; d[2] = cs2; d[3] = cs3;
        }
    }
    __syncthreads();
    {
        int p  = t >> 4;
        int c0 = l16 * 4;
#pragma unroll
        for (int k = 0; k < 4; ++k) {
            float v = smem[p * 256 +       c0 + k] + smem[p * 256 +  64 + c0 + k]
                    + smem[p * 256 + 128 + c0 + k] + smem[p * 256 + 192 + c0 + k];
            xw[(p0 + p) * 64 + c0 + k] = v * 0.015625f;
        }
    }
    __syncthreads();

    // ---- grid barrier (all 256 blocks) ----
    if (t == 0) {
        __threadfence();
        atomicAdd(bar, 1u);
        while (atomicAdd(bar, 0u) < GRID) { __builtin_amdgcn_s_sleep(2); }
        __threadfence();
    }
    __syncthreads();

    // ---- Phase 2a: yl[m][p] = hswish(BN(W1 @ pool_n)) ----
    int p2 = t & 127;
    int mg = (t >> 7) * 4;                        // wave-uniform
    float acc0 = 0.f, acc1 = 0.f, acc2 = 0.f, acc3 = 0.f;
    for (int cc = 0; cc < 8; ++cc) {
        int c0 = cc * 32;
        __syncthreads();
#pragma unroll
        for (int i = 0; i < 16; ++i) {
            int ci = i * 2 + (t >> 7);
            int c  = c0 + ci;
            float v = (p2 < 64)
                ? xh[((size_t)(n * 256 + c)) * 64 + p2]
                : xw[((size_t)(n * 256 + c)) * 64 + p2 - 64];
            smem[ci * 128 + p2] = v;
        }
        __syncthreads();
#pragma unroll
        for (int ci = 0; ci < 32; ++ci) {
            float pv = smem[ci * 128 + p2];
            int c = c0 + ci;
            acc0 += pv * w1[(mg + 0) * 256 + c];
            acc1 += pv * w1[(mg + 1) * 256 + c];
            acc2 += pv * w1[(mg + 2) * 256 + c];
            acc3 += pv * w1[(mg + 3) * 256 + c];
        }
    }
    {
        float a[4] = {acc0, acc1, acc2, acc3};
#pragma unroll
        for (int k = 0; k < 4; ++k) {
            int m = mg + k;
            float yv  = a[k] + b1[m];
            float inv = gamma[m] * rsqrtf(var[m] + EPSV);
            yv = (yv - mean[m]) * inv + beta[m];
            float cl = fminf(fmaxf(yv + 3.f, 0.f), 6.f);
            yl[m * 128 + p2] = yv * cl * (1.f / 6.f);
        }
    }
    __syncthreads();

    // ---- Phase 2b: ah/aw for this block's 16 planes ----
    {
        int pi = t >> 4;
        int o  = (blk & 15) * 16 + pi;
#pragma unroll
        for (int k = 0; k < 4; ++k) {
            int h = l16 * 4 + k;
            float acch = b2[o], accw = b3[o];
#pragma unroll
            for (int m = 0; m < MIP; ++m) {
                acch += w2[o * MIP + m] * yl[m * 128 + h];
                accw += w3[o * MIP + m] * yl[m * 128 + 64 + h];
            }
            ah_l[pi * 64 + h] = 1.f / (1.f + __expf(-acch));
            aw_l[pi * 64 + h] = 1.f / (1.f + __expf(-accw));
        }
    }
    __syncthreads();

    // ---- Phase 3: out = wei2*s + (2-wei2)*res, wei2 = 2*ah*aw ----
#pragma unroll
    for (int p = 0; p < PPB; ++p) {
        float4 aw4 = *(const float4*)&aw_l[p * 64 + l16 * 4];
#pragma unroll
        for (int j = 0; j < 4; ++j) {
            float4 r = pr4[p * 1024 + j * 256 + t];
            float ah2 = 2.f * ah_l[p * 64 + j * 16 + g16];
            float w0 = ah2 * aw4.x, w1v = ah2 * aw4.y;
            float w2v = ah2 * aw4.z, w3v = ah2 * aw4.w;
            float4 o4;
            o4.x = w0  * s[p][j].x + (2.f - w0)  * r.x;
            o4.y = w1v * s[p][j].y + (2.f - w1v) * r.y;
            o4.z = w2v * s[p][j].z + (2.f - w2v) * r.z;
            o4.w = w3v * s[p][j].w + (2.f - w3v) * r.w;
            po4[p * 1024 + j * 256 + t] = o4;
        }
    }
}

extern "C" void kernel_launch(void* const* d_in, const int* in_sizes, int n_in,
                              void* d_out, int out_size, void* d_ws, size_t ws_size,
                              hipStream_t stream) {
    const float* x     = (const float*)d_in[0];
    const float* res   = (const float*)d_in[1];
    const float* w1    = (const float*)d_in[2];
    const float* b1    = (const float*)d_in[3];
    const float* gamma = (const float*)d_in[4];
    const float* beta  = (const float*)d_in[5];
    const float* mean  = (const float*)d_in[6];
    const float* var   = (const float*)d_in[7];
    const float* w2    = (const float*)d_in[8];
    const float* b2    = (const float*)d_in[9];
    const float* w3    = (const float*)d_in[10];
    const float* b3    = (const float*)d_in[11];
    float* out = (float*)d_out;

    float* ws = (float*)d_ws;
    float* xh = ws;                       // 4096 planes * 64 = 262144 floats
    float* xw = ws + 262144;              // 262144 floats
    unsigned* bar = (unsigned*)(ws + 524288);

    hipMemsetAsync(bar, 0, 64, stream);
    k_fused<<<GRID, 256, 0, stream>>>(x, res, w1, b1, gamma, beta, mean, var,
                                      w2, b2, w3, b3, out, xh, xw, bar);
}

// Round 10
// 71.228 us; speedup vs baseline: 1.9412x; 1.9412x over previous
//
#include <hip/hip_runtime.h>
#include <math.h>

#define NB 16
#define CB 256
#define MIP 8
#define EPSV 1e-5f

// K1: per (n,c) plane: row means (over w) -> xh[n][c][h], col means (over h) -> xw[n][c][w]
// Plane order REVERSED within each XCD (zig-zag): k_apply (ascending) left low
// planes hottest in each XCD's L2 at iteration boundaries, and our tail leaves
// low planes hot for k_apply's head.
__global__ __launch_bounds__(256) void k_reduce(const float* __restrict__ x,
                                                const float* __restrict__ res,
                                                float* __restrict__ xh,
                                                float* __restrict__ xw) {
    int bid = blockIdx.x;
    int plane = (bid & 7) + 8 * (511 - (bid >> 3));   // same XCD as bid, reversed order
    const float4* px4 = (const float4*)(x   + (size_t)plane * 4096);
    const float4* pr4 = (const float4*)(res + (size_t)plane * 4096);
    __shared__ float spad[256];
    int t = threadIdx.x;

    float4 a[4], b[4];
#pragma unroll
    for (int i = 0; i < 4; i++) a[i] = px4[i * 256 + t];
#pragma unroll
    for (int i = 0; i < 4; i++) b[i] = pr4[i * 256 + t];

    float csum0 = 0.f, csum1 = 0.f, csum2 = 0.f, csum3 = 0.f;
    float rsum[4];
#pragma unroll
    for (int i = 0; i < 4; i++) {
        float s0 = a[i].x + b[i].x, s1 = a[i].y + b[i].y;
        float s2 = a[i].z + b[i].z, s3 = a[i].w + b[i].w;
        csum0 += s0; csum1 += s1; csum2 += s2; csum3 += s3;
        rsum[i] = (s0 + s1) + (s2 + s3);
    }

    // rows: reduce each rsum[i] across the 16 lanes sharing row i*16+(t>>4)
#pragma unroll
    for (int i = 0; i < 4; i++) {
        float rs = rsum[i];
        rs += __shfl_xor(rs, 1);
        rs += __shfl_xor(rs, 2);
        rs += __shfl_xor(rs, 4);
        rs += __shfl_xor(rs, 8);
        rsum[i] = rs;
    }
    if ((t & 15) == 0) {
        int g = t >> 4;                           // 0..15
#pragma unroll
        for (int i = 0; i < 4; i++)
            xh[(size_t)plane * 64 + i * 16 + g] = rsum[i] * 0.015625f;
    }

    // cols: combine the 4 row-groups within each wave (lane bits 4,5), then LDS
    csum0 += __shfl_xor(csum0, 16); csum0 += __shfl_xor(csum0, 32);
    csum1 += __shfl_xor(csum1, 16); csum1 += __shfl_xor(csum1, 32);
    csum2 += __shfl_xor(csum2, 16); csum2 += __shfl_xor(csum2, 32);
    csum3 += __shfl_xor(csum3, 16); csum3 += __shfl_xor(csum3, 32);
    int wv = t >> 6;                              // wave 0..3
    int j  = t & 15;
    if ((t & 63) < 16) {
        float* d = &spad[wv * 64 + j * 4];
        d[0] = csum0; d[1] = csum1; d[2] = csum2; d[3] = csum3;
    }
    __syncthreads();
    if (t < 64)
        xw[(size_t)plane * 64 + t] =
            (spad[t] + spad[64 + t] + spad[128 + t] + spad[192 + t]) * 0.015625f;
}

// K2: per n: yl[n][m][p] = hswish(BN(W1*pool + b1)), p in [0,128)  (p<64: from xh, else xw)
__global__ __launch_bounds__(256) void k_mid_a(const float* __restrict__ xh,
                                               const float* __restrict__ xw,
                                               const float* __restrict__ w1,
                                               const float* __restrict__ b1,
                                               const float* __restrict__ gamma,
                                               const float* __restrict__ beta,
                                               const float* __restrict__ mean,
                                               const float* __restrict__ var,
                                               float* __restrict__ yl) {
    int n = blockIdx.x;
    int t = threadIdx.x;
    int p  = t & 127;
    int mg = (t >> 7) * 4;  // 0 or 4 (wave-uniform)
    const float* pool = (p < 64) ? (xh + (size_t)n * CB * 64 + p)
                                 : (xw + (size_t)n * CB * 64 + (p - 64));
    float acc[4] = {0.f, 0.f, 0.f, 0.f};
    for (int c = 0; c < CB; c++) {
        float pv = pool[(size_t)c * 64];
#pragma unroll
        for (int k = 0; k < 4; k++) acc[k] += pv * w1[(mg + k) * CB + c];
    }
#pragma unroll
    for (int k = 0; k < 4; k++) {
        int m = mg + k;
        float yv = acc[k] + b1[m];
        float inv = gamma[m] * rsqrtf(var[m] + EPSV);
        yv = (yv - mean[m]) * inv + beta[m];
        float cl = fminf(fmaxf(yv + 3.f, 0.f), 6.f);
        yl[((size_t)n * MIP + m) * 128 + p] = yv * cl * (1.f / 6.f);
    }
}

// K3: per (n,o) plane: prologue computes ah[h], aw[w] from yl/w2/w3, then
//     out = 2*wei*x + 2*res, wei = ah[h]*aw[w].  Ascending plane order.
__global__ __launch_bounds__(256) void k_apply(const float* __restrict__ x,
                                               const float* __restrict__ res,
                                               const float* __restrict__ yl,
                                               const float* __restrict__ w2,
                                               const float* __restrict__ b2,
                                               const float* __restrict__ w3,
                                               const float* __restrict__ b3,
                                               float* __restrict__ out) {
    int plane = blockIdx.x;                       // n*256 + o
    int n = plane >> 8;
    int o = plane & 255;
    const float4* px4 = (const float4*)(x   + (size_t)plane * 4096);
    const float4* pr4 = (const float4*)(res + (size_t)plane * 4096);
    float4*       po4 = (float4*)(out + (size_t)plane * 4096);
    __shared__ float sah[64], saw[64];
    int t = threadIdx.x;
    if (t < 128) {
        int hh  = t & 63;
        int off = (t < 64) ? 0 : 64;
        const float* wv = (t < 64) ? (w2 + o * MIP) : (w3 + o * MIP);
        float acc = (t < 64) ? b2[o] : b3[o];
        const float* ylp = yl + (size_t)n * MIP * 128 + off + hh;
#pragma unroll
        for (int m = 0; m < MIP; m++) acc += ylp[m * 128] * wv[m];
        float sig = 1.f / (1.f + __expf(-acc));
        if (t < 64) sah[hh] = sig; else saw[hh] = sig;
    }
    __syncthreads();
    const float4 sw4 = *(const float4*)&saw[4 * (t & 15)];
#pragma unroll
    for (int i = 0; i < 4; i++) {
        int row = i * 16 + (t >> 4);
        float ahr2 = 2.f * sah[row];
        float4 a = px4[i * 256 + t];
        float4 b = pr4[i * 256 + t];
        float4 oo;
        oo.x = a.x * (ahr2 * sw4.x) + 2.f * b.x;
        oo.y = a.y * (ahr2 * sw4.y) + 2.f * b.y;
        oo.z = a.z * (ahr2 * sw4.z) + 2.f * b.z;
        oo.w = a.w * (ahr2 * sw4.w) + 2.f * b.w;
        po4[i * 256 + t] = oo;
    }
}

extern "C" void kernel_launch(void* const* d_in, const int* in_sizes, int n_in,
                              void* d_out, int out_size, void* d_ws, size_t ws_size,
                              hipStream_t stream) {
    const float* x     = (const float*)d_in[0];
    const float* res   = (const float*)d_in[1];
    const float* w1    = (const float*)d_in[2];
    const float* b1    = (const float*)d_in[3];
    const float* gamma = (const float*)d_in[4];
    const float* beta  = (const float*)d_in[5];
    const float* mean  = (const float*)d_in[6];
    const float* var   = (const float*)d_in[7];
    const float* w2    = (const float*)d_in[8];
    const float* b2    = (const float*)d_in[9];
    const float* w3    = (const float*)d_in[10];
    const float* b3    = (const float*)d_in[11];
    float* out = (float*)d_out;

    float* ws = (float*)d_ws;
    float* xh = ws;                 // 16*256*64 = 262144 floats
    float* xw = ws + 262144;        // 262144 floats
    float* yl = ws + 524288;        // 16*8*128 = 16384 floats

    k_reduce<<<NB * CB, 256, 0, stream>>>(x, res, xh, xw);
    k_mid_a<<<NB, 256, 0, stream>>>(xh, xw, w1, b1, gamma, beta, mean, var, yl);
    k_apply<<<NB * CB, 256, 0, stream>>>(x, res, yl, w2, b2, w3, b3, out);
}

// Round 11
// 57.122 us; speedup vs baseline: 2.4206x; 1.2469x over previous
//
#include <hip/hip_runtime.h>
#include <math.h>

#define NB 16
#define CB 256
#define MIP 8
#define EPSV 1e-5f

// K1: per (n,c) plane: row means (over w) -> xh[n][c][h], col means (over h) -> xw[n][c][w]
// Plane order REVERSED within each XCD (zig-zag vs k_apply's ascending order):
// k_apply's tail leaves high planes L2-hot for our head next iteration, and our
// tail leaves low planes hot for k_apply's head this iteration.
__global__ __launch_bounds__(256) void k_reduce(const float* __restrict__ x,
                                                const float* __restrict__ res,
                                                float* __restrict__ xh,
                                                float* __restrict__ xw) {
    int bid = blockIdx.x;
    int plane = (bid & 7) + 8 * (511 - (bid >> 3));   // same XCD as bid, reversed order
    const float4* px4 = (const float4*)(x   + (size_t)plane * 4096);
    const float4* pr4 = (const float4*)(res + (size_t)plane * 4096);
    __shared__ float spad[256];
    int t = threadIdx.x;

    float4 a[4], b[4];
#pragma unroll
    for (int i = 0; i < 4; i++) a[i] = px4[i * 256 + t];
#pragma unroll
    for (int i = 0; i < 4; i++) b[i] = pr4[i * 256 + t];

    float csum0 = 0.f, csum1 = 0.f, csum2 = 0.f, csum3 = 0.f;
    float rsum[4];
#pragma unroll
    for (int i = 0; i < 4; i++) {
        float s0 = a[i].x + b[i].x, s1 = a[i].y + b[i].y;
        float s2 = a[i].z + b[i].z, s3 = a[i].w + b[i].w;
        csum0 += s0; csum1 += s1; csum2 += s2; csum3 += s3;
        rsum[i] = (s0 + s1) + (s2 + s3);
    }
#pragma unroll
    for (int i = 0; i < 4; i++) {
        float rs = rsum[i];
        rs += __shfl_xor(rs, 1);
        rs += __shfl_xor(rs, 2);
        rs += __shfl_xor(rs, 4);
        rs += __shfl_xor(rs, 8);
        rsum[i] = rs;
    }
    if ((t & 15) == 0) {
        int g = t >> 4;
#pragma unroll
        for (int i = 0; i < 4; i++)
            xh[(size_t)plane * 64 + i * 16 + g] = rsum[i] * 0.015625f;
    }
    csum0 += __shfl_xor(csum0, 16); csum0 += __shfl_xor(csum0, 32);
    csum1 += __shfl_xor(csum1, 16); csum1 += __shfl_xor(csum1, 32);
    csum2 += __shfl_xor(csum2, 16); csum2 += __shfl_xor(csum2, 32);
    csum3 += __shfl_xor(csum3, 16); csum3 += __shfl_xor(csum3, 32);
    int wv = t >> 6;
    int j  = t & 15;
    if ((t & 63) < 16) {
        float* d = &spad[wv * 64 + j * 4];
        d[0] = csum0; d[1] = csum1; d[2] = csum2; d[3] = csum3;
    }
    __syncthreads();
    if (t < 64)
        xw[(size_t)plane * 64 + t] =
            (spad[t] + spad[64 + t] + spad[128 + t] + spad[192 + t]) * 0.015625f;
}

// K2: grid = NB*8 blocks. Block (n, pc) covers p in [pc*16, pc*16+16).
// Computes yl[m][p] = hswish(BN(W1 @ pool)) for its p-range (c-split + LDS
// combine), then the full sigmoid layer at those p's:
//   pc<4  -> ah[n][o][p]      for all o
//   pc>=4 -> aw[n][o][p-64]   for all o
__global__ __launch_bounds__(256) void k_mid(const float* __restrict__ xh,
                                             const float* __restrict__ xw,
                                             const float* __restrict__ w1,
                                             const float* __restrict__ b1,
                                             const float* __restrict__ gamma,
                                             const float* __restrict__ beta,
                                             const float* __restrict__ mean,
                                             const float* __restrict__ var,
                                             const float* __restrict__ w2,
                                             const float* __restrict__ b2,
                                             const float* __restrict__ w3,
                                             const float* __restrict__ b3,
                                             float* __restrict__ ah,
                                             float* __restrict__ aw) {
    int n  = blockIdx.x >> 3;
    int pc = blockIdx.x & 7;
    int t  = threadIdx.x;
    int ph = t & 15;                    // p within chunk
    int p  = pc * 16 + ph;              // p in [0,128)
    int m  = (t >> 4) & 7;
    int half = t >> 7;                  // c-range half
    __shared__ float part[256];
    __shared__ float ylds[MIP * 16];

    const float* pool = (p < 64) ? (xh + ((size_t)n * CB) * 64 + p)
                                 : (xw + ((size_t)n * CB) * 64 + (p - 64));
    float acc = 0.f;
    int c0 = half * 128;
#pragma unroll 16
    for (int ci = 0; ci < 128; ci++) {
        int c = c0 + ci;
        acc += pool[(size_t)c * 64] * w1[m * CB + c];
    }
    part[t] = acc;
    __syncthreads();
    if (t < 128) {
        float val = part[t] + part[t + 128] + b1[m];
        float inv = gamma[m] * rsqrtf(var[m] + EPSV);
        val = (val - mean[m]) * inv + beta[m];
        float cl = fminf(fmaxf(val + 3.f, 0.f), 6.f);
        ylds[m * 16 + ph] = val * cl * (1.f / 6.f);
    }
    __syncthreads();

    // sigmoid layer: 256 o x 16 p outputs for this block
    const float* wsel = (p < 64) ? w2 : w3;
    const float* bsel = (p < 64) ? b2 : b3;
    float* osel = (p < 64) ? (ah + ((size_t)n * CB) * 64 + p)
                           : (aw + ((size_t)n * CB) * 64 + (p - 64));
#pragma unroll
    for (int oo = 0; oo < 16; oo++) {
        int o = oo * 16 + (t >> 4);
        float acc2 = bsel[o];
#pragma unroll
        for (int mm = 0; mm < MIP; mm++)
            acc2 += wsel[o * MIP + mm] * ylds[mm * 16 + ph];
        osel[(size_t)o * 64] = 1.f / (1.f + __expf(-acc2));
    }
}

// K3: per (n,o) plane: load ah/aw (precomputed), out = 2*wei*x + 2*res.
__global__ __launch_bounds__(256) void k_apply(const float* __restrict__ x,
                                               const float* __restrict__ res,
                                               const float* __restrict__ ah,
                                               const float* __restrict__ aw,
                                               float* __restrict__ out) {
    int plane = blockIdx.x;                       // n*256 + o
    const float4* px4 = (const float4*)(x   + (size_t)plane * 4096);
    const float4* pr4 = (const float4*)(res + (size_t)plane * 4096);
    float4*       po4 = (float4*)(out + (size_t)plane * 4096);
    __shared__ float sah[64], saw[64];
    int t = threadIdx.x;
    if (t < 64)       sah[t]      = ah[(size_t)plane * 64 + t];
    else if (t < 128) saw[t - 64] = aw[(size_t)plane * 64 + (t - 64)];
    __syncthreads();
    const float4 sw4 = *(const float4*)&saw[4 * (t & 15)];
#pragma unroll
    for (int i = 0; i < 4; i++) {
        int row = i * 16 + (t >> 4);
        float ahr2 = 2.f * sah[row];
        float4 a = px4[i * 256 + t];
        float4 b = pr4[i * 256 + t];
        float4 oo;
        oo.x = a.x * (ahr2 * sw4.x) + 2.f * b.x;
        oo.y = a.y * (ahr2 * sw4.y) + 2.f * b.y;
        oo.z = a.z * (ahr2 * sw4.z) + 2.f * b.z;
        oo.w = a.w * (ahr2 * sw4.w) + 2.f * b.w;
        po4[i * 256 + t] = oo;
    }
}

extern "C" void kernel_launch(void* const* d_in, const int* in_sizes, int n_in,
                              void* d_out, int out_size, void* d_ws, size_t ws_size,
                              hipStream_t stream) {
    const float* x     = (const float*)d_in[0];
    const float* res   = (const float*)d_in[1];
    const float* w1    = (const float*)d_in[2];
    const float* b1    = (const float*)d_in[3];
    const float* gamma = (const float*)d_in[4];
    const float* beta  = (const float*)d_in[5];
    const float* mean  = (const float*)d_in[6];
    const float* var   = (const float*)d_in[7];
    const float* w2    = (const float*)d_in[8];
    const float* b2    = (const float*)d_in[9];
    const float* w3    = (const float*)d_in[10];
    const float* b3    = (const float*)d_in[11];
    float* out = (float*)d_out;

    float* ws = (float*)d_ws;
    float* xh = ws;                 // 16*256*64 = 262144 floats
    float* xw = ws + 262144;
    float* ah = ws + 524288;
    float* aw = ws + 786432;        // total 4 MiB

    k_reduce<<<NB * CB, 256, 0, stream>>>(x, res, xh, xw);
    k_mid<<<NB * 8, 256, 0, stream>>>(xh, xw, w1, b1, gamma, beta, mean, var,
                                      w2, b2, w3, b3, ah, aw);
    k_apply<<<NB * CB, 256, 0, stream>>>(x, res, ah, aw, out);
}